// Round 2
// baseline (697.351 us; speedup 1.0000x reference)
//
#include <hip/hip_runtime.h>

#define NPG 148      // nodes per graph
#define EPG 592      // edges per graph
#define S   36       // LDS row stride (floats) for both node buffers (max Fi=32 + pad)

// One block = one graph. Aggregate-first formulation:
//   t[n]   = dis[n] * h[n]                      (Fi-wide, in-place)
//   agg[d] = t[d] + sum_{s->d} t[s]             (LDS float atomics, self-loop = init)
//   h'[d]  = relu(dis[d] * agg[d] @ W + b)      (register-tiled matmul)

template<int Fi, int Fo, bool LAST>
__device__ __forceinline__ void gcn_layer(int t,
    const float* __restrict__ sW, const float* __restrict__ sB,
    float* __restrict__ bin, float* __restrict__ bagg,
    const int* __restrict__ s_edge, const float* __restrict__ s_dis,
    const float* __restrict__ gW, float* __restrict__ gout)
{
    // ---- Phase A: th = dis*in (in place) and agg init (self-loop term) ----
    constexpr int F4 = Fi / 4;
    for (int item = t; item < NPG * F4; item += 256) {
        const int n = item / F4;
        const int c = (item % F4) * 4;
        float4 v = *reinterpret_cast<const float4*>(&bin[n * S + c]);
        const float dn = s_dis[n];
        v.x *= dn; v.y *= dn; v.z *= dn; v.w *= dn;
        *reinterpret_cast<float4*>(&bin[n * S + c])  = v;
        *reinterpret_cast<float4*>(&bagg[n * S + c]) = v;
    }
    __syncthreads();

    // ---- Phase B: edge aggregation via LDS float atomics ----
    for (int item = t; item < EPG * Fi; item += 256) {
        const int e = item / Fi;          // Fi is a power of 2 -> shift
        const int c = item & (Fi - 1);
        const int pk = s_edge[e];
        const int s = pk & 0xFF;
        const int d = pk >> 8;
        atomicAdd(&bagg[d * S + c], bin[s * S + c]);
    }
    __syncthreads();

    // ---- Phase C: matmul, 4-node x 8-col register tile ----
    constexpr int OG = Fo / 8;
    constexpr int ITEMS = (NPG / 4) * OG;   // 37 * OG
    for (int item = t; item < ITEMS; item += 256) {
        const int n0 = (item / OG) * 4;
        const int ob = (item % OG) * 8;
        float acc[4][8];
        #pragma unroll
        for (int j = 0; j < 4; ++j)
            #pragma unroll
            for (int c = 0; c < 8; ++c) acc[j][c] = 0.f;

        #pragma unroll
        for (int k = 0; k < Fi; k += 4) {
            float av[4][4];
            #pragma unroll
            for (int j = 0; j < 4; ++j) {
                const float4 a = *reinterpret_cast<const float4*>(&bagg[(n0 + j) * S + k]);
                av[j][0] = a.x; av[j][1] = a.y; av[j][2] = a.z; av[j][3] = a.w;
            }
            #pragma unroll
            for (int kk = 0; kk < 4; ++kk) {
                const float* Wrow = (LAST ? gW : sW) + (k + kk) * Fo + ob;
                const float4 w0 = *reinterpret_cast<const float4*>(Wrow);
                const float4 w1 = *reinterpret_cast<const float4*>(Wrow + 4);
                const float wv[8] = {w0.x, w0.y, w0.z, w0.w, w1.x, w1.y, w1.z, w1.w};
                #pragma unroll
                for (int j = 0; j < 4; ++j)
                    #pragma unroll
                    for (int c = 0; c < 8; ++c)
                        acc[j][c] = fmaf(av[j][kk], wv[c], acc[j][c]);
            }
        }
        #pragma unroll
        for (int j = 0; j < 4; ++j) {
            const float dn = s_dis[n0 + j];
            float4 v0, v1;
            v0.x = fmaxf(fmaf(acc[j][0], dn, sB[ob + 0]), 0.f);
            v0.y = fmaxf(fmaf(acc[j][1], dn, sB[ob + 1]), 0.f);
            v0.z = fmaxf(fmaf(acc[j][2], dn, sB[ob + 2]), 0.f);
            v0.w = fmaxf(fmaf(acc[j][3], dn, sB[ob + 3]), 0.f);
            v1.x = fmaxf(fmaf(acc[j][4], dn, sB[ob + 4]), 0.f);
            v1.y = fmaxf(fmaf(acc[j][5], dn, sB[ob + 5]), 0.f);
            v1.z = fmaxf(fmaf(acc[j][6], dn, sB[ob + 6]), 0.f);
            v1.w = fmaxf(fmaf(acc[j][7], dn, sB[ob + 7]), 0.f);
            if (LAST) {
                *reinterpret_cast<float4*>(&gout[(n0 + j) * 64 + ob])     = v0;
                *reinterpret_cast<float4*>(&gout[(n0 + j) * 64 + ob + 4]) = v1;
            } else {
                *reinterpret_cast<float4*>(&bin[(n0 + j) * S + ob])     = v0;
                *reinterpret_cast<float4*>(&bin[(n0 + j) * S + ob + 4]) = v1;
            }
        }
    }
    if (!LAST) __syncthreads();
}

__global__ __launch_bounds__(256, 3)
void gcn_fused(const float* __restrict__ x,
               const int* __restrict__ esrc, const int* __restrict__ edst,
               const float* __restrict__ W1, const float* __restrict__ b1,
               const float* __restrict__ W2, const float* __restrict__ b2,
               const float* __restrict__ W3, const float* __restrict__ b3,
               float* __restrict__ out)
{
    __shared__ float bufA[NPG * S];       // layer input / th (in-place)
    __shared__ float bufB[NPG * S];       // aggregation accumulator
    __shared__ int   s_edge[EPG];         // packed src | dst<<8
    __shared__ float s_dis[NPG];          // 1/sqrt(deg)
    __shared__ int   s_cnt[NPG];
    __shared__ float s_W[64 + 512];       // W1 | W2  (W3 stays in global/L1)
    __shared__ float s_b[16 + 32 + 64];

    const int t  = threadIdx.x;
    const int g  = blockIdx.x;
    const int be = g * EPG;
    const int bn = g * NPG;

    if (t < NPG) s_cnt[t] = 0;
    __syncthreads();

    // load edges (localized, packed) + count in-degree
    for (int e = t; e < EPG; e += 256) {
        const int s = esrc[be + e] - bn;
        const int d = edst[be + e] - bn;
        s_edge[e] = s | (d << 8);
        atomicAdd(&s_cnt[d], 1);
    }
    // stage weights / biases / x
    for (int i = t; i < 64;  i += 256) s_W[i]      = W1[i];
    for (int i = t; i < 512; i += 256) s_W[64 + i] = W2[i];
    if (t < 16) s_b[t]      = b1[t];
    if (t < 32) s_b[16 + t] = b2[t];
    if (t < 64) s_b[48 + t] = b3[t];
    if (t < NPG) {
        const float4 v = reinterpret_cast<const float4*>(x)[bn + t];
        *reinterpret_cast<float4*>(&bufA[t * S]) = v;
    }
    __syncthreads();

    if (t < NPG) s_dis[t] = rsqrtf((float)(s_cnt[t] + 1));
    __syncthreads();

    float* gout = out + (size_t)bn * 64;
    gcn_layer< 4, 16, false>(t, s_W,      s_b,      bufA, bufB, s_edge, s_dis, nullptr, nullptr);
    gcn_layer<16, 32, false>(t, s_W + 64, s_b + 16, bufA, bufB, s_edge, s_dis, nullptr, nullptr);
    gcn_layer<32, 64, true >(t, nullptr,  s_b + 48, bufA, bufB, s_edge, s_dis, W3, gout);
}

extern "C" void kernel_launch(void* const* d_in, const int* in_sizes, int n_in,
                              void* d_out, int out_size, void* d_ws, size_t ws_size,
                              hipStream_t stream)
{
    const float* x  = (const float*)d_in[0];
    const int*   ei = (const int*)d_in[1];
    const float* W1 = (const float*)d_in[3];
    const float* b1 = (const float*)d_in[4];
    const float* W2 = (const float*)d_in[5];
    const float* b2 = (const float*)d_in[6];
    const float* W3 = (const float*)d_in[7];
    const float* b3 = (const float*)d_in[8];
    float* out = (float*)d_out;

    const int N = in_sizes[0] / 4;     // total nodes
    const int B = N / NPG;             // graphs
    const int E = in_sizes[1] / 2;     // total edges

    gcn_fused<<<B, 256, 0, stream>>>(x, ei, ei + E, W1, b1, W2, b2, W3, b3, out);
}

// Round 3
// 130.389 us; speedup vs baseline: 5.3482x; 5.3482x over previous
//
#include <hip/hip_runtime.h>

#define NPG 148      // nodes per graph
#define EPG 592      // edges per graph
#define S   36       // dword stride of node rows (32 + pad)
#define NTHR 256

__device__ __forceinline__ float4 ld4(const float* p) { return *reinterpret_cast<const float4*>(p); }
__device__ __forceinline__ void st4(float* p, float4 v) { *reinterpret_cast<float4*>(p) = v; }

// One block = one graph. Aggregate-first:
//   agg[d] = dis[d] * ( dis[d]*h[d] + sum_{s->d} dis[s]*h[s] )   (CSR gather -> regs -> in-place writeback)
//   h'[d]  = relu(agg[d] @ W + b)                                (register-tiled matmul, in-place)

template<int Fi, int Fo, int NT, int CT, bool LAST>
__device__ __forceinline__ void gcn_layer(int t,
    const float* __restrict__ sW, const float* __restrict__ sB,
    float* __restrict__ bin,
    const int* __restrict__ s_csr, const int* __restrict__ s_row,
    const float* __restrict__ s_dis,
    const float* __restrict__ gW, float* __restrict__ gout)
{
    // ---- Phase G: normalized aggregation into registers ----
    constexpr int F4 = Fi / 4;
    constexpr int GITEMS = NPG * F4;                    // 148 / 592 / 1184
    constexpr int NSLOT = (GITEMS + NTHR - 1) / NTHR;   // 1 / 3 / 5
    float4 racc[NSLOT];
    #pragma unroll
    for (int sl = 0; sl < NSLOT; ++sl) {
        const int item = t + sl * NTHR;
        if (item < GITEMS) {
            const int d   = item / F4;
            const int col = (item & (F4 - 1)) * 4;
            float4 a = ld4(&bin[d * S + col]);
            const float dd = s_dis[d];
            a.x *= dd; a.y *= dd; a.z *= dd; a.w *= dd;
            const int e1 = s_row[d + 1];
            for (int e = s_row[d]; e < e1; ++e) {
                const int sidx = s_csr[e];
                const float ds = s_dis[sidx];
                const float4 m = ld4(&bin[sidx * S + col]);
                a.x = fmaf(m.x, ds, a.x);
                a.y = fmaf(m.y, ds, a.y);
                a.z = fmaf(m.z, ds, a.z);
                a.w = fmaf(m.w, ds, a.w);
            }
            a.x *= dd; a.y *= dd; a.z *= dd; a.w *= dd;   // outer norm folded here
            racc[sl] = a;
        }
    }
    __syncthreads();
    #pragma unroll
    for (int sl = 0; sl < NSLOT; ++sl) {
        const int item = t + sl * NTHR;
        if (item < GITEMS)
            st4(&bin[(item / F4) * S + (item & (F4 - 1)) * 4], racc[sl]);
    }
    __syncthreads();

    // ---- Phase M: matmul, NT-node x CT-col register tile ----
    constexpr int OG = Fo / CT;                 // col-groups per n-group
    constexpr int MITEMS = (NPG / NT) * OG;     // 148 / 148 / 296
    for (int item = t; item < MITEMS; item += NTHR) {
        const int ng = item / OG;
        const int n0 = ng * NT;
        const int ob = (item % OG) * CT;
        const int kbase = (ng & 7) * 4;         // de-conflict A-reads across n-groups
        float acc[NT][CT];
        #pragma unroll
        for (int j = 0; j < NT; ++j)
            #pragma unroll
            for (int c = 0; c < CT; ++c) acc[j][c] = 0.f;

        #pragma unroll
        for (int ki = 0; ki < Fi; ki += 4) {
            const int k = (ki + kbase) & (Fi - 1);
            float av[NT][4];
            #pragma unroll
            for (int j = 0; j < NT; ++j) {
                const float4 a = ld4(&bin[(n0 + j) * S + k]);
                av[j][0] = a.x; av[j][1] = a.y; av[j][2] = a.z; av[j][3] = a.w;
            }
            #pragma unroll
            for (int kk = 0; kk < 4; ++kk) {
                const float* Wrow = (LAST ? gW : sW) + (k + kk) * Fo + ob;
                float wv[CT];
                #pragma unroll
                for (int c = 0; c < CT; c += 4) {
                    const float4 w = ld4(Wrow + c);
                    wv[c] = w.x; wv[c + 1] = w.y; wv[c + 2] = w.z; wv[c + 3] = w.w;
                }
                #pragma unroll
                for (int j = 0; j < NT; ++j)
                    #pragma unroll
                    for (int c = 0; c < CT; ++c)
                        acc[j][c] = fmaf(av[j][kk], wv[c], acc[j][c]);
            }
        }
        #pragma unroll
        for (int j = 0; j < NT; ++j) {
            #pragma unroll
            for (int c = 0; c < CT; c += 4) {
                float4 v;
                v.x = fmaxf(acc[j][c + 0] + sB[ob + c + 0], 0.f);
                v.y = fmaxf(acc[j][c + 1] + sB[ob + c + 1], 0.f);
                v.z = fmaxf(acc[j][c + 2] + sB[ob + c + 2], 0.f);
                v.w = fmaxf(acc[j][c + 3] + sB[ob + c + 3], 0.f);
                if (LAST) st4(&gout[(n0 + j) * 64 + ob + c], v);
                else      st4(&bin[(n0 + j) * S + ob + c], v);
            }
        }
    }
    if (!LAST) __syncthreads();
}

__global__ __launch_bounds__(256, 5)
void gcn_fused(const float* __restrict__ x,
               const int* __restrict__ esrc, const int* __restrict__ edst,
               const float* __restrict__ W1, const float* __restrict__ b1,
               const float* __restrict__ W2, const float* __restrict__ b2,
               const float* __restrict__ W3, const float* __restrict__ b3,
               float* __restrict__ out)
{
    __shared__ float bin[NPG * S];        // 21.3 KB node buffer (in-place all layers)
    __shared__ int   s_csr[EPG];
    __shared__ int   s_edge[EPG];         // packed src | dst<<8
    __shared__ int   s_row[NPG + 2];
    __shared__ float s_dis[NPG];
    __shared__ int   s_cnt[NPG];
    __shared__ int   s_cnt2[NPG];
    __shared__ float s_W[64 + 512];       // W1 | W2 (W3 stays global: L1/L2-hot)
    __shared__ float s_b[16 + 32 + 64];

    const int t  = threadIdx.x;
    const int g  = blockIdx.x;
    const int be = g * EPG;
    const int bn = g * NPG;

    if (t < NPG) { s_cnt[t] = 0; s_cnt2[t] = 0; }
    __syncthreads();                                     // bar0

    // ---- load edges (packed, localized) + in-degree count; stage W/b/x ----
    #pragma unroll
    for (int e = t; e < EPG; e += NTHR) {
        const int s = esrc[be + e] - bn;
        const int d = edst[be + e] - bn;
        s_edge[e] = s | (d << 8);
        atomicAdd(&s_cnt[d], 1);
    }
    for (int i = t; i < 64;  i += NTHR) s_W[i]      = W1[i];
    for (int i = t; i < 512; i += NTHR) s_W[64 + i] = W2[i];
    if (t < 16)                  s_b[t]            = b1[t];
    else if (t >= 32 && t < 64)  s_b[16 + t - 32]  = b2[t - 32];
    else if (t >= 64 && t < 128) s_b[48 + t - 64]  = b3[t - 64];
    if (t < NPG)
        st4(&bin[t * S], reinterpret_cast<const float4*>(x)[bn + t]);
    __syncthreads();                                     // bar1

    // ---- dis + single-wave shfl prefix scan (exclusive row offsets) ----
    if (t < NPG) s_dis[t] = rsqrtf((float)(s_cnt[t] + 1));
    if (t < 64) {
        const int lane = t;
        int v0 = s_cnt[lane];                            // positions 0..63
        int v1 = s_cnt[64 + lane];                       // positions 64..127
        int v2 = (128 + lane < NPG) ? s_cnt[128 + lane] : 0;  // 128..147
        #pragma unroll
        for (int off = 1; off < 64; off <<= 1) {
            const int u0 = __shfl_up(v0, off);
            const int u1 = __shfl_up(v1, off);
            const int u2 = __shfl_up(v2, off);
            if (lane >= off) { v0 += u0; v1 += u1; v2 += u2; }
        }
        const int t0 = __shfl(v0, 63);
        const int t1 = __shfl(v1, 63);
        v1 += t0;
        v2 += t0 + t1;
        if (lane == 0) s_row[0] = 0;
        s_row[1 + lane]  = v0;
        s_row[65 + lane] = v1;
        if (128 + lane < NPG) s_row[129 + lane] = v2;
    }
    __syncthreads();                                     // bar2

    // ---- scatter edges into CSR ----
    #pragma unroll
    for (int e = t; e < EPG; e += NTHR) {
        const int pk = s_edge[e];
        const int s  = pk & 0xFF;
        const int d  = pk >> 8;
        const int pos = s_row[d] + atomicAdd(&s_cnt2[d], 1);
        s_csr[pos] = s;
    }
    __syncthreads();                                     // bar3

    float* gout = out + (size_t)bn * 64;
    gcn_layer< 4, 16, 2, 8, false>(t, s_W,      s_b,      bin, s_csr, s_row, s_dis, nullptr, nullptr);
    gcn_layer<16, 32, 4, 8, false>(t, s_W + 64, s_b + 16, bin, s_csr, s_row, s_dis, nullptr, nullptr);
    gcn_layer<32, 64, 4, 8, true >(t, nullptr,  s_b + 48, bin, s_csr, s_row, s_dis, W3, gout);
}

extern "C" void kernel_launch(void* const* d_in, const int* in_sizes, int n_in,
                              void* d_out, int out_size, void* d_ws, size_t ws_size,
                              hipStream_t stream)
{
    const float* x  = (const float*)d_in[0];
    const int*   ei = (const int*)d_in[1];
    const float* W1 = (const float*)d_in[3];
    const float* b1 = (const float*)d_in[4];
    const float* W2 = (const float*)d_in[5];
    const float* b2 = (const float*)d_in[6];
    const float* W3 = (const float*)d_in[7];
    const float* b3 = (const float*)d_in[8];
    float* out = (float*)d_out;

    const int N = in_sizes[0] / 4;     // total nodes
    const int B = N / NPG;             // graphs
    const int E = in_sizes[1] / 2;     // total edges

    gcn_fused<<<B, NTHR, 0, stream>>>(x, ei, ei + E, W1, b1, W2, b2, W3, b3, out);
}

// Round 4
// 66.304 us; speedup vs baseline: 10.5175x; 1.9665x over previous
//
#include <hip/hip_runtime.h>

#define NPG 148      // nodes per graph
#define EPG 592      // edges per graph
#define NTHR 256
#define SA   40      // f16 stride of A16/Wt rows (32 + 8 pad -> 2-way max bank alias)
#define MT   10      // M row-tiles (148 -> 160 padded)

typedef _Float16 h8 __attribute__((ext_vector_type(8)));
typedef _Float16 h4 __attribute__((ext_vector_type(4)));
typedef float    f4 __attribute__((ext_vector_type(4)));

// One block = one graph. Per layer:
//   G: agg[d] = dis[d]*(dis[d]*h[d] + sum_{s->d} dis[s]*h[s])   f32 regs over f16 LDS reads
//   M: h'[.]  = relu(agg @ W + b) via one v_mfma_f32_16x16x32_f16 per 16x16 tile
// A16 [160][SA] f16 holds node features in-place across layers (K-cols zero-padded).
// Wt holds W^T f16, rows zero-padded to K=32 so a B-frag is one b128 read.

template<int Fi, int Fo, int KC, int NTN, int MAXJ, int NSLOT, int WROW, int BOFF, bool LAST>
__device__ __forceinline__ void layer(int t,
    _Float16* __restrict__ A16, const _Float16* __restrict__ Wt,
    const float* __restrict__ s_b, const int* __restrict__ s_csr,
    const int* __restrict__ s_row, const float* __restrict__ s_dis,
    float* __restrict__ gout)
{
    constexpr int GITEMS = NPG * KC;

    // ---- Phase G: normalized aggregation into f32 registers ----
    float r[NSLOT][8];
    #pragma unroll
    for (int sl = 0; sl < NSLOT; ++sl) {
        const int item = t + sl * NTHR;
        if (item < GITEMS) {
            const int d  = item / KC;       // KC is power of 2
            const int kc = item % KC;
            const h8 hv = *reinterpret_cast<const h8*>(&A16[d * SA + kc * 8]);
            const float dd = s_dis[d];
            float a[8];
            #pragma unroll
            for (int u = 0; u < 8; ++u) a[u] = dd * (float)hv[u];
            const int e1 = s_row[d + 1];
            for (int e = s_row[d]; e < e1; ++e) {
                const int sidx = s_csr[e];
                const float ds = s_dis[sidx];
                const h8 m = *reinterpret_cast<const h8*>(&A16[sidx * SA + kc * 8]);
                #pragma unroll
                for (int u = 0; u < 8; ++u) a[u] = fmaf((float)m[u], ds, a[u]);
            }
            #pragma unroll
            for (int u = 0; u < 8; ++u) r[sl][u] = a[u] * dd;
        }
    }
    __syncthreads();
    #pragma unroll
    for (int sl = 0; sl < NSLOT; ++sl) {
        const int item = t + sl * NTHR;
        if (item < GITEMS) {
            const int d  = item / KC;
            const int kc = item % KC;
            h8 pv;
            #pragma unroll
            for (int u = 0; u < 8; ++u) pv[u] = (_Float16)r[sl][u];
            *reinterpret_cast<h8*>(&A16[d * SA + kc * 8]) = pv;
        }
    }
    __syncthreads();

    // ---- Phase M: MFMA matmul. Pre-load all fragments, barrier, then compute+write ----
    const int w   = t >> 6;
    const int l16 = t & 15;
    const int q   = (t >> 4) & 3;
    h8 af[MAXJ], bf[MAXJ];
    #pragma unroll
    for (int j = 0; j < MAXJ; ++j) {
        const int idx = w + 4 * j;
        if (idx < MT * NTN) {
            const int mt = idx / NTN, nt = idx % NTN;
            af[j] = *reinterpret_cast<const h8*>(&A16[(mt * 16 + l16) * SA + q * 8]);
            bf[j] = *reinterpret_cast<const h8*>(&Wt[(WROW + nt * 16 + l16) * SA + q * 8]);
        }
    }
    __syncthreads();
    #pragma unroll
    for (int j = 0; j < MAXJ; ++j) {
        const int idx = w + 4 * j;
        if (idx < MT * NTN) {
            const int mt = idx / NTN, nt = idx % NTN;
            f4 acc = {0.f, 0.f, 0.f, 0.f};
            acc = __builtin_amdgcn_mfma_f32_16x16x32_f16(af[j], bf[j], acc, 0, 0, 0);
            const int col  = nt * 16 + l16;
            const float bias = s_b[BOFF + col];
            #pragma unroll
            for (int rr = 0; rr < 4; ++rr) {
                const float v = fmaxf(acc[rr] + bias, 0.f);
                const int row = mt * 16 + q * 4 + rr;
                if (LAST) {
                    if (row < NPG) gout[row * 64 + col] = v;   // 64B-segment coalesced
                } else {
                    A16[row * SA + col] = (_Float16)v;         // pad rows harmless
                }
            }
        }
    }
    if (!LAST) __syncthreads();
}

__global__ __launch_bounds__(256, 4)
void gcn_fused(const float* __restrict__ x,
               const int* __restrict__ esrc, const int* __restrict__ edst,
               const float* __restrict__ W1, const float* __restrict__ b1,
               const float* __restrict__ W2, const float* __restrict__ b2,
               const float* __restrict__ W3, const float* __restrict__ b3,
               float* __restrict__ out)
{
    __shared__ __align__(16) _Float16 A16[160 * SA];   // 12.8 KB node features (f16)
    __shared__ __align__(16) _Float16 Wt[112 * SA];    // 9 KB: W1t rows 0..15 | W2t 16..47 | W3t 48..111
    __shared__ float s_b[112];                         // b1 | b2 | b3
    __shared__ int   s_csr[EPG];
    __shared__ int   s_edge[EPG];
    __shared__ int   s_row[NPG + 2];
    __shared__ float s_dis[NPG];
    __shared__ int   s_cnt[NPG], s_cnt2[NPG];

    const int t  = threadIdx.x;
    const int g  = blockIdx.x;
    const int be = g * EPG;
    const int bn = g * NPG;

    // ---- zero f16 buffers (K-padding + M-padding must be 0) and counters ----
    for (int i = t; i < 160 * SA / 8; i += NTHR) reinterpret_cast<f4*>(A16)[i] = f4{0.f, 0.f, 0.f, 0.f};
    for (int i = t; i < 112 * SA / 8; i += NTHR) reinterpret_cast<f4*>(Wt)[i]  = f4{0.f, 0.f, 0.f, 0.f};
    if (t < NPG) { s_cnt[t] = 0; s_cnt2[t] = 0; }
    __syncthreads();

    // ---- edges (localized, packed) + degree count; stage W^T f16, bias, x f16 ----
    for (int e = t; e < EPG; e += NTHR) {
        const int s = esrc[be + e] - bn;
        const int d = edst[be + e] - bn;
        s_edge[e] = s | (d << 8);
        atomicAdd(&s_cnt[d], 1);
    }
    for (int i = t; i < 64;   i += NTHR) Wt[(i & 15) * SA + (i >> 4)]        = (_Float16)W1[i];
    for (int i = t; i < 512;  i += NTHR) Wt[(16 + (i & 31)) * SA + (i >> 5)] = (_Float16)W2[i];
    for (int i = t; i < 2048; i += NTHR) Wt[(48 + (i & 63)) * SA + (i >> 6)] = (_Float16)W3[i];
    if (t < 16)       s_b[t] = b1[t];
    else if (t < 48)  s_b[t] = b2[t - 16];
    else if (t < 112) s_b[t] = b3[t - 48];
    if (t < NPG) {
        const float4 xv = reinterpret_cast<const float4*>(x)[bn + t];
        h4 p; p[0] = (_Float16)xv.x; p[1] = (_Float16)xv.y; p[2] = (_Float16)xv.z; p[3] = (_Float16)xv.w;
        *reinterpret_cast<h4*>(&A16[t * SA]) = p;
    }
    __syncthreads();

    // ---- dis + single-wave shfl prefix scan -> CSR row offsets ----
    if (t < NPG) s_dis[t] = rsqrtf((float)(s_cnt[t] + 1));
    if (t < 64) {
        const int lane = t;
        int v0 = s_cnt[lane];
        int v1 = s_cnt[64 + lane];
        int v2 = (128 + lane < NPG) ? s_cnt[128 + lane] : 0;
        #pragma unroll
        for (int off = 1; off < 64; off <<= 1) {
            const int u0 = __shfl_up(v0, off);
            const int u1 = __shfl_up(v1, off);
            const int u2 = __shfl_up(v2, off);
            if (lane >= off) { v0 += u0; v1 += u1; v2 += u2; }
        }
        const int t0 = __shfl(v0, 63);
        const int t1 = __shfl(v1, 63);
        v1 += t0;
        v2 += t0 + t1;
        if (lane == 0) s_row[0] = 0;
        s_row[1 + lane]  = v0;
        s_row[65 + lane] = v1;
        if (128 + lane < NPG) s_row[129 + lane] = v2;
    }
    __syncthreads();

    // ---- scatter edges into CSR ----
    for (int e = t; e < EPG; e += NTHR) {
        const int pk = s_edge[e];
        const int s  = pk & 0xFF;
        const int d  = pk >> 8;
        const int pos = s_row[d] + atomicAdd(&s_cnt2[d], 1);
        s_csr[pos] = s;
    }
    __syncthreads();

    float* gout = out + (size_t)bn * 64;
    //     Fi  Fo  KC NTN MAXJ NSLOT WROW BOFF LAST
    layer< 4, 16,  1,  1,   3,   1,    0,   0, false>(t, A16, Wt, s_b, s_csr, s_row, s_dis, gout);
    layer<16, 32,  2,  2,   5,   2,   16,  16, false>(t, A16, Wt, s_b, s_csr, s_row, s_dis, gout);
    layer<32, 64,  4,  4,  10,   3,   48,  48, true >(t, A16, Wt, s_b, s_csr, s_row, s_dis, gout);
}

extern "C" void kernel_launch(void* const* d_in, const int* in_sizes, int n_in,
                              void* d_out, int out_size, void* d_ws, size_t ws_size,
                              hipStream_t stream)
{
    const float* x  = (const float*)d_in[0];
    const int*   ei = (const int*)d_in[1];
    const float* W1 = (const float*)d_in[3];
    const float* b1 = (const float*)d_in[4];
    const float* W2 = (const float*)d_in[5];
    const float* b2 = (const float*)d_in[6];
    const float* W3 = (const float*)d_in[7];
    const float* b3 = (const float*)d_in[8];
    float* out = (float*)d_out;

    const int N = in_sizes[0] / 4;     // total nodes
    const int B = N / NPG;             // graphs
    const int E = in_sizes[1] / 2;     // total edges

    gcn_fused<<<B, NTHR, 0, stream>>>(x, ei, ei + E, W1, b1, W2, b2, W3, b3, out);
}

// Round 5
// 63.230 us; speedup vs baseline: 11.0289x; 1.0486x over previous
//
#include <hip/hip_runtime.h>

#define NPG 148      // nodes per graph
#define EPG 592      // edges per graph
#define NTHR 256
#define SA   40      // f16 stride of A16/Wt rows (32 + 8 pad); 80 B, 16B-aligned
#define MT   10      // M row-tiles (148 -> 160 padded)

typedef _Float16 h8 __attribute__((ext_vector_type(8)));
typedef _Float16 h4 __attribute__((ext_vector_type(4)));
typedef float    f4 __attribute__((ext_vector_type(4)));

// One block = one graph.
//   G: agg[d] = dis[d]*(dis[d]*h[d] + sum_{s->d} dis[s]*h[s])  (degree-sorted CSR gather, f32 regs)
//   M: h' = relu(agg @ W + b) via v_mfma_f32_16x16x32_f16
// s_meta[d] (degree-sorted): .x = rowByteOff | disF16<<16 ; .y = csrStart | csrEnd<<16
// s_csr[e]:                        srcByteOff | disF16<<16

template<int Fi, int Fo, int KC, int NTN, int MAXJ, int NSLOT, int WROW, int BOFF, bool LAST>
__device__ __forceinline__ void layer(int t,
    _Float16* __restrict__ A16, const _Float16* __restrict__ Wt,
    const float* __restrict__ s_b, const uint2* __restrict__ s_meta,
    const unsigned int* __restrict__ s_csr, float* __restrict__ gout)
{
    constexpr int GITEMS = NPG * KC;

    // ---- Phase G ----
    float r[NSLOT][8];
    int   ro[NSLOT];
    #pragma unroll
    for (int sl = 0; sl < NSLOT; ++sl) {
        const int item = t + sl * NTHR;
        if (item < GITEMS) {
            const int d  = item / KC;
            const int kc = item & (KC - 1);
            const uint2 me = s_meta[d];
            const int off = (int)(me.x & 0xffffu) + kc * 16;
            ro[sl] = off;
            const h8 hv = *reinterpret_cast<const h8*>(reinterpret_cast<const char*>(A16) + off);
            const float dd = (float)__builtin_bit_cast(_Float16, (unsigned short)(me.x >> 16));
            float a[8];
            #pragma unroll
            for (int u = 0; u < 8; ++u) a[u] = dd * (float)hv[u];
            const int e1 = (int)(me.y >> 16);
            for (int e = (int)(me.y & 0xffffu); e < e1; ++e) {
                const unsigned int pk = s_csr[e];
                const h8 m = *reinterpret_cast<const h8*>(
                    reinterpret_cast<const char*>(A16) + (pk & 0xffffu) + kc * 16);
                const float ds = (float)__builtin_bit_cast(_Float16, (unsigned short)(pk >> 16));
                #pragma unroll
                for (int u = 0; u < 8; ++u) a[u] = fmaf((float)m[u], ds, a[u]);
            }
            #pragma unroll
            for (int u = 0; u < 8; ++u) r[sl][u] = a[u] * dd;
        }
    }
    __syncthreads();
    #pragma unroll
    for (int sl = 0; sl < NSLOT; ++sl) {
        const int item = t + sl * NTHR;
        if (item < GITEMS) {
            h8 pv;
            #pragma unroll
            for (int u = 0; u < 8; ++u) pv[u] = (_Float16)r[sl][u];
            *reinterpret_cast<h8*>(reinterpret_cast<char*>(A16) + ro[sl]) = pv;
        }
    }
    __syncthreads();

    // ---- Phase M: MFMA. Pre-load fragments, barrier, compute+write ----
    const int w   = t >> 6;
    const int l16 = t & 15;
    const int q   = (t >> 4) & 3;
    h8 af[MAXJ], bf[MAXJ];
    #pragma unroll
    for (int j = 0; j < MAXJ; ++j) {
        const int idx = w + 4 * j;
        if (idx < MT * NTN) {
            const int mt = idx / NTN, nt = idx % NTN;
            af[j] = *reinterpret_cast<const h8*>(&A16[(mt * 16 + l16) * SA + q * 8]);
            bf[j] = *reinterpret_cast<const h8*>(&Wt[(WROW + nt * 16 + l16) * SA + q * 8]);
        }
    }
    __syncthreads();
    #pragma unroll
    for (int j = 0; j < MAXJ; ++j) {
        const int idx = w + 4 * j;
        if (idx < MT * NTN) {
            const int mt = idx / NTN, nt = idx % NTN;
            f4 acc = {0.f, 0.f, 0.f, 0.f};
            acc = __builtin_amdgcn_mfma_f32_16x16x32_f16(af[j], bf[j], acc, 0, 0, 0);
            const int col  = nt * 16 + l16;
            const float bias = s_b[BOFF + col];
            #pragma unroll
            for (int rr = 0; rr < 4; ++rr) {
                const float v = fmaxf(acc[rr] + bias, 0.f);
                const int row = mt * 16 + q * 4 + rr;
                if (LAST) {
                    if (row < NPG) gout[row * 64 + col] = v;
                } else {
                    A16[row * SA + col] = (_Float16)v;
                }
            }
        }
    }
    if (!LAST) __syncthreads();
}

__global__ __launch_bounds__(256, 5)
void gcn_fused(const float* __restrict__ x,
               const int* __restrict__ esrc, const int* __restrict__ edst,
               const float* __restrict__ W1, const float* __restrict__ b1,
               const float* __restrict__ W2, const float* __restrict__ b2,
               const float* __restrict__ W3, const float* __restrict__ b3,
               float* __restrict__ out)
{
    __shared__ __align__(16) _Float16 A16[160 * SA];   // 12.8 KB
    __shared__ __align__(16) _Float16 Wt[112 * SA];    // 9.0 KB
    __shared__ float s_b[112];
    __shared__ unsigned int s_csr[EPG];
    __shared__ int   s_edge[EPG];
    __shared__ int   s_row[NPG + 2];
    __shared__ unsigned int s_dish[NPG];               // disF16 pre-shifted <<16
    __shared__ uint2 s_meta[NPG];                      // degree-sorted node metadata
    __shared__ int   s_cnt[NPG], s_cnt2[NPG];
    __shared__ int   s_hist[64], s_boff[64], s_bcnt[64];

    const int t  = threadIdx.x;
    const int g  = blockIdx.x;
    const int be = g * EPG;
    const int bn = g * NPG;

    // ---- zero f16 buffers (K/M padding must be 0) and counters ----
    for (int i = t; i < 160 * SA / 8; i += NTHR) reinterpret_cast<f4*>(A16)[i] = f4{0.f, 0.f, 0.f, 0.f};
    for (int i = t; i < 112 * SA / 8; i += NTHR) reinterpret_cast<f4*>(Wt)[i]  = f4{0.f, 0.f, 0.f, 0.f};
    if (t < NPG) { s_cnt[t] = 0; s_cnt2[t] = 0; }
    if (t < 64)  { s_hist[t] = 0; s_bcnt[t] = 0; }
    __syncthreads();

    // ---- edges (localized, packed) + degree count; stage W^T f16, bias, x f16 ----
    for (int e = t; e < EPG; e += NTHR) {
        const int s = esrc[be + e] - bn;
        const int d = edst[be + e] - bn;
        s_edge[e] = s | (d << 8);
        atomicAdd(&s_cnt[d], 1);
    }
    for (int i = t; i < 64;   i += NTHR) Wt[(i & 15) * SA + (i >> 4)]        = (_Float16)W1[i];
    for (int i = t; i < 512;  i += NTHR) Wt[(16 + (i & 31)) * SA + (i >> 5)] = (_Float16)W2[i];
    for (int i = t; i < 2048; i += NTHR) Wt[(48 + (i & 63)) * SA + (i >> 6)] = (_Float16)W3[i];
    if (t < 16)       s_b[t] = b1[t];
    else if (t < 48)  s_b[t] = b2[t - 16];
    else if (t < 112) s_b[t] = b3[t - 48];
    if (t < NPG) {
        const float4 xv = reinterpret_cast<const float4*>(x)[bn + t];
        h4 p; p[0] = (_Float16)xv.x; p[1] = (_Float16)xv.y; p[2] = (_Float16)xv.z; p[3] = (_Float16)xv.w;
        *reinterpret_cast<h4*>(&A16[t * SA]) = p;
    }
    __syncthreads();

    // ---- dis (f16, pre-shifted) + degree histogram ----
    if (t < NPG) {
        const int deg = s_cnt[t];
        const float disf = rsqrtf((float)(deg + 1));
        s_dish[t] = ((unsigned int)__builtin_bit_cast(unsigned short, (_Float16)disf)) << 16;
        atomicAdd(&s_hist[min(deg, 63)], 1);
    }
    __syncthreads();

    // ---- wave 0: CSR offset scan (148) ; wave 1: degree-bucket scan (64) ----
    if (t < 64) {
        const int lane = t;
        int v0 = s_cnt[lane];
        int v1 = s_cnt[64 + lane];
        int v2 = (128 + lane < NPG) ? s_cnt[128 + lane] : 0;
        #pragma unroll
        for (int off = 1; off < 64; off <<= 1) {
            const int u0 = __shfl_up(v0, off);
            const int u1 = __shfl_up(v1, off);
            const int u2 = __shfl_up(v2, off);
            if (lane >= off) { v0 += u0; v1 += u1; v2 += u2; }
        }
        const int t0 = __shfl(v0, 63);
        const int t1 = __shfl(v1, 63);
        v1 += t0;
        v2 += t0 + t1;
        if (lane == 0) s_row[0] = 0;
        s_row[1 + lane]  = v0;
        s_row[65 + lane] = v1;
        if (128 + lane < NPG) s_row[129 + lane] = v2;
    } else if (t < 128) {
        const int lane = t - 64;
        const int orig = s_hist[lane];
        int v = orig;
        #pragma unroll
        for (int off = 1; off < 64; off <<= 1) {
            const int u = __shfl_up(v, off);
            if (lane >= off) v += u;
        }
        s_boff[lane] = v - orig;     // exclusive prefix
    }
    __syncthreads();

    // ---- scatter: packed CSR entries + degree-sorted meta ----
    for (int e = t; e < EPG; e += NTHR) {
        const int pk = s_edge[e];
        const int s  = pk & 0xFF;
        const int d  = pk >> 8;
        const int pos = s_row[d] + atomicAdd(&s_cnt2[d], 1);
        s_csr[pos] = (unsigned int)(s * (SA * 2)) | s_dish[s];
    }
    if (t < NPG) {
        const int deg = s_cnt[t];
        const int b   = min(deg, 63);
        const int p   = s_boff[b] + atomicAdd(&s_bcnt[b], 1);
        s_meta[p] = make_uint2((unsigned int)(t * (SA * 2)) | s_dish[t],
                               (unsigned int)s_row[t] | ((unsigned int)s_row[t + 1] << 16));
    }
    __syncthreads();

    float* gout = out + (size_t)bn * 64;
    //     Fi  Fo  KC NTN MAXJ NSLOT WROW BOFF LAST
    layer< 4, 16,  1,  1,   3,   1,    0,   0, false>(t, A16, Wt, s_b, s_meta, s_csr, gout);
    layer<16, 32,  2,  2,   5,   2,   16,  16, false>(t, A16, Wt, s_b, s_meta, s_csr, gout);
    layer<32, 64,  4,  4,  10,   3,   48,  48, true >(t, A16, Wt, s_b, s_meta, s_csr, gout);
}

extern "C" void kernel_launch(void* const* d_in, const int* in_sizes, int n_in,
                              void* d_out, int out_size, void* d_ws, size_t ws_size,
                              hipStream_t stream)
{
    const float* x  = (const float*)d_in[0];
    const int*   ei = (const int*)d_in[1];
    const float* W1 = (const float*)d_in[3];
    const float* b1 = (const float*)d_in[4];
    const float* W2 = (const float*)d_in[5];
    const float* b2 = (const float*)d_in[6];
    const float* W3 = (const float*)d_in[7];
    const float* b3 = (const float*)d_in[8];
    float* out = (float*)d_out;

    const int N = in_sizes[0] / 4;     // total nodes
    const int B = N / NPG;             // graphs
    const int E = in_sizes[1] / 2;     // total edges

    gcn_fused<<<B, NTHR, 0, stream>>>(x, ei, ei + E, W1, b1, W2, b2, W3, b3, out);
}